// Round 4
// baseline (327.010 us; speedup 1.0000x reference)
//
#include <hip/hip_runtime.h>
#include <cstdint>
#include <cstddef>

// ---------------- problem constants ----------------
#define SCALEQ 0.17677669529663689f // 32^-0.5

typedef _Float16 half_t;
typedef _Float16 half8   __attribute__((ext_vector_type(8)));
typedef _Float16 half4v  __attribute__((ext_vector_type(4)));
typedef float    float4v __attribute__((ext_vector_type(4)));

#define GLDS16(gp, lp)                                                        \
  __builtin_amdgcn_global_load_lds(                                           \
      (const __attribute__((address_space(1))) void*)(gp),                    \
      (__attribute__((address_space(3))) void*)(lp), 16, 0, 0)

// ---------------- prep kernels (unchanged, verified) ----------------
__global__ void prep_convw(const float* __restrict__ w, half_t* __restrict__ Wt) {
  int idx = blockIdx.x * 256 + threadIdx.x;           // < 589824
  int tap = idx >> 16, rem = idx & 65535;
  int o = rem >> 8, c = rem & 255;
  Wt[idx] = (half_t)w[(o * 256 + c) * 9 + tap];
}

__global__ void prep_qkvw(const float* __restrict__ w, half_t* __restrict__ W16) {
  int idx = blockIdx.x * 256 + threadIdx.x;           // < 196608
  float v = w[idx];
  if (idx < 65536) v *= SCALEQ;                       // q rows pre-scaled
  W16[idx] = (half_t)v;
}

__global__ void prep_projw(const float* __restrict__ w, half_t* __restrict__ W16) {
  int idx = blockIdx.x * 256 + threadIdx.x;           // < 65536
  W16[idx] = (half_t)w[idx];
}

__global__ void prep_bias(const float* __restrict__ rpb, float* __restrict__ btab) {
  int idx = blockIdx.x * 256 + threadIdx.x;           // < 32768
  int hd = idx >> 12, n = (idx >> 6) & 63, m = idx & 63;
  int h1 = n >> 3, w1 = n & 7, h2 = m >> 3, w2 = m & 7;
  int ridx = (h1 - h2 + 7) * 15 + (w1 - w2 + 7);
  btab[idx] = rpb[ridx * 8 + hd];
}

__global__ void prep_xpad(const float* __restrict__ x, half_t* __restrict__ xpad) {
  __shared__ float tile[128 * 65];
  int bd = blockIdx.x, b = bd / 100, d = bd % 100;
  int t = threadIdx.x;
  for (int hf = 0; hf < 2; ++hf) {
    for (int i = 0; i < 32; ++i) {
      int idx = i * 256 + t, c = idx >> 6, hw = idx & 63;
      tile[c * 65 + hw] = x[(size_t)((b * 256 + hf * 128 + c) * 100 + d) * 64 + hw];
    }
    __syncthreads();
    for (int i = 0; i < 50; ++i) {
      int idx = i * 256 + t, cell = idx >> 7, c = idx & 127;
      int hh = cell / 10, ww = cell % 10;
      float v = 0.f;
      if (hh >= 1 && hh <= 8 && ww >= 1 && ww <= 8)
        v = tile[c * 65 + (hh - 1) * 8 + (ww - 1)];
      xpad[(size_t)(bd * 100 + cell) * 256 + hf * 128 + c] = (half_t)v;
    }
    __syncthreads();
  }
}

// ---------------- conv implicit GEMM (unchanged, verified) ----------------
__global__ __launch_bounds__(256) void conv_kernel(
    const half_t* __restrict__ Wt, const half_t* __restrict__ xpad,
    const float* __restrict__ convb, half_t* __restrict__ xl) {
  __shared__ __align__(16) half_t Asm[128 * 64];
  __shared__ __align__(16) half_t Bsm[128 * 64];
  const int blk = blockIdx.x;
  const int o0 = (blk & 1) * 128;
  const int n0 = (blk >> 1) * 128;
  const int tid = threadIdx.x;
  const int wave = tid >> 6, lane = tid & 63;
  const int l15 = lane & 15, quad = lane >> 4;
  const int wm = wave >> 1, wn = wave & 1;
  const int srow = tid >> 3;
  const int cg = (tid & 7) ^ (srow & 7);

  int pixbase[4], arow[4];
#pragma unroll
  for (int i = 0; i < 4; ++i) {
    int P = n0 + srow + i * 32;
    int bd = P >> 6, hw = P & 63;
    pixbase[i] = (bd * 100 + (hw >> 3) * 10 + (hw & 7)) * 512 + cg * 16;
    arow[i] = (o0 + srow + i * 32) * 512 + cg * 16;
  }

  float4v acc[4][4];
#pragma unroll
  for (int mi = 0; mi < 4; ++mi)
#pragma unroll
    for (int ni = 0; ni < 4; ++ni) {
      float4v z = {0.f, 0.f, 0.f, 0.f};
      acc[mi][ni] = z;
    }

  const char* xpc = (const char*)xpad;
  for (int tap = 0; tap < 9; ++tap) {
    const char* wt = (const char*)Wt + tap * 131072;
    const int toff = ((tap / 3) * 10 + (tap % 3)) * 512;
    for (int c0 = 0; c0 < 512; c0 += 128) {
#pragma unroll
      for (int i = 0; i < 4; ++i) {
        GLDS16(wt + arow[i] + c0, (char*)Asm + i * 4096 + wave * 1024);
        GLDS16(xpc + pixbase[i] + toff + c0, (char*)Bsm + i * 4096 + wave * 1024);
      }
      __syncthreads();
#pragma unroll
      for (int kh = 0; kh < 2; ++kh) {
        half8 af[4], bf[4];
#pragma unroll
        for (int mi = 0; mi < 4; ++mi) {
          int r = wm * 64 + mi * 16 + l15;
          af[mi] = *(const half8*)&Asm[r * 64 + (((kh * 4 + quad) ^ (r & 7)) * 8)];
        }
#pragma unroll
        for (int ni = 0; ni < 4; ++ni) {
          int r = wn * 64 + ni * 16 + l15;
          bf[ni] = *(const half8*)&Bsm[r * 64 + (((kh * 4 + quad) ^ (r & 7)) * 8)];
        }
#pragma unroll
        for (int mi = 0; mi < 4; ++mi)
#pragma unroll
          for (int ni = 0; ni < 4; ++ni)
            acc[mi][ni] = __builtin_amdgcn_mfma_f32_16x16x32_f16(
                af[mi], bf[ni], acc[mi][ni], 0, 0, 0);
      }
      __syncthreads();
    }
  }
#pragma unroll
  for (int mi = 0; mi < 4; ++mi) {
    const int o4 = o0 + wm * 64 + mi * 16 + quad * 4;
    const float b0 = convb[o4], b1 = convb[o4 + 1], b2 = convb[o4 + 2], b3 = convb[o4 + 3];
#pragma unroll
    for (int ni = 0; ni < 4; ++ni) {
      const int P = n0 + wn * 64 + ni * 16 + l15;
      half4v h;
      h.x = (half_t)(acc[mi][ni].x + b0);
      h.y = (half_t)(acc[mi][ni].y + b1);
      h.z = (half_t)(acc[mi][ni].z + b2);
      h.w = (half_t)(acc[mi][ni].w + b3);
      *(half4v*)(xl + (size_t)P * 256 + o4) = h;
    }
  }
}

// ---------------- fused qkv + attention ----------------
// grid 800 (one bd slice), block 512 (8 waves = 1 wave per head).
// After one staging barrier, waves are fully independent: each computes its
// head's q/k/v (W streamed from L2), round-trips through wave-PRIVATE LDS
// scratch (same-wave waitcnt only, no barriers), then QK->softmax->PV.
// LDS: xlp [0,32768) = xl[64px][256] swizzled; per-wave scratch 15360 B:
//   q [64px][40] @0, k [64px][40] @5120, v [32hd][72] @10240, P [64][72] @0.
__global__ __launch_bounds__(512, 2) void fused_qkv_attn(
    const half_t* __restrict__ xlg, const half_t* __restrict__ qw,
    const float* __restrict__ qkvb, const float* __restrict__ btab,
    half_t* __restrict__ xa) {
  __shared__ __align__(16) half_t LS[77824];  // 155648 B
  const int bd = blockIdx.x;
  const int tid = threadIdx.x;
  const int wave = tid >> 6, lane = tid & 63;
  const int l15 = lane & 15, quad = lane >> 4;
  const int head = wave;

  half_t* xlp = LS;
  half_t* scr = LS + 16384 + wave * 7680;   // halves: 15360 B per wave
  half_t* qsc = scr;                         // [64][40]
  half_t* ksc = scr + 2560;                  // [64][40]
  half_t* vsc = scr + 5120;                  // [32][72]
  half_t* Psc = scr;                         // [64][72] (over q+k)

  // ---- stage xl[bd] (32 KB), XOR-swizzled 16B chunks ----
  {
    const char* src = (const char*)(xlg + (size_t)bd * 64 * 256);
#pragma unroll
    for (int i = 0; i < 4; ++i) {
      int row = i * 16 + wave * 2 + (lane >> 5);
      int sch = (lane & 31) ^ (row & 7);
      GLDS16(src + row * 512 + sch * 16, (char*)xlp + (i * 16 + wave * 2) * 512);
    }
  }
  __syncthreads();   // ONLY block-wide barrier

  // ---- q and k GEMMs: M=32 (head rows), N=64 px, K=256 ----
  for (int p = 0; p < 2; ++p) {
    const half_t* Wp = qw + p * 65536 + head * 32 * 256;
    float4v acc[2][4];
#pragma unroll
    for (int mi = 0; mi < 2; ++mi)
#pragma unroll
      for (int ni = 0; ni < 4; ++ni) {
        float4v z = {0.f, 0.f, 0.f, 0.f};
        acc[mi][ni] = z;
      }
#pragma unroll
    for (int kh = 0; kh < 8; ++kh) {
      half8 af[2], bf[4];
#pragma unroll
      for (int mi = 0; mi < 2; ++mi)
        af[mi] = *(const half8*)(Wp + (mi * 16 + l15) * 256 + kh * 32 + quad * 8);
#pragma unroll
      for (int ni = 0; ni < 4; ++ni) {
        int r = ni * 16 + l15;
        bf[ni] = *(const half8*)&xlp[r * 256 + (((kh * 4 + quad) ^ (r & 7)) * 8)];
      }
#pragma unroll
      for (int mi = 0; mi < 2; ++mi)
#pragma unroll
        for (int ni = 0; ni < 4; ++ni)
          acc[mi][ni] = __builtin_amdgcn_mfma_f32_16x16x32_f16(
              af[mi], bf[ni], acc[mi][ni], 0, 0, 0);
    }
    // epilogue: + bias (q pre-scaled weights, bias scaled here) -> scratch [px][40]
    half_t* dst = (p == 0) ? qsc : ksc;
    const float sc = (p == 0) ? SCALEQ : 1.0f;
#pragma unroll
    for (int mi = 0; mi < 2; ++mi) {
      const float4v b4 = *(const float4v*)&qkvb[p * 256 + head * 32 + mi * 16 + quad * 4];
#pragma unroll
      for (int ni = 0; ni < 4; ++ni) {
        half4v h;
        h.x = (half_t)(acc[mi][ni].x + b4.x * sc);
        h.y = (half_t)(acc[mi][ni].y + b4.y * sc);
        h.z = (half_t)(acc[mi][ni].z + b4.z * sc);
        h.w = (half_t)(acc[mi][ni].w + b4.w * sc);
        *(half4v*)(dst + (ni * 16 + l15) * 40 + mi * 16 + quad * 4) = h;
      }
    }
  }

  // ---- v GEMM: D[hd][px] -> vsc [32][72] (scalar b16 writes) ----
  {
    const half_t* Wp = qw + 2 * 65536 + head * 32 * 256;
    float4v acc[2][4];
#pragma unroll
    for (int mi = 0; mi < 2; ++mi)
#pragma unroll
      for (int ni = 0; ni < 4; ++ni) {
        float4v z = {0.f, 0.f, 0.f, 0.f};
        acc[mi][ni] = z;
      }
#pragma unroll
    for (int kh = 0; kh < 8; ++kh) {
      half8 af[2], bf[4];
#pragma unroll
      for (int mi = 0; mi < 2; ++mi)
        af[mi] = *(const half8*)(Wp + (mi * 16 + l15) * 256 + kh * 32 + quad * 8);
#pragma unroll
      for (int ni = 0; ni < 4; ++ni) {
        int r = ni * 16 + l15;
        bf[ni] = *(const half8*)&xlp[r * 256 + (((kh * 4 + quad) ^ (r & 7)) * 8)];
      }
#pragma unroll
      for (int mi = 0; mi < 2; ++mi)
#pragma unroll
        for (int ni = 0; ni < 4; ++ni)
          acc[mi][ni] = __builtin_amdgcn_mfma_f32_16x16x32_f16(
              af[mi], bf[ni], acc[mi][ni], 0, 0, 0);
    }
#pragma unroll
    for (int mi = 0; mi < 2; ++mi) {
      const float4v b4 = *(const float4v*)&qkvb[512 + head * 32 + mi * 16 + quad * 4];
#pragma unroll
      for (int ni = 0; ni < 4; ++ni) {
#pragma unroll
        for (int iv = 0; iv < 4; ++iv)
          vsc[(mi * 16 + quad * 4 + iv) * 72 + ni * 16 + l15] =
              (half_t)(acc[mi][ni][iv] + b4[iv]);
      }
    }
  }

  __builtin_amdgcn_s_waitcnt(0);  // q/k/v scratch writes -> visible to own reads

  // ---- QK^T + bias + softmax (round-1 verified, strides 40/72) ----
  half8 aq[4], bk[4];
#pragma unroll
  for (int i = 0; i < 4; ++i) {
    aq[i] = *(const half8*)(qsc + (i * 16 + l15) * 40 + quad * 8);
    bk[i] = *(const half8*)(ksc + (i * 16 + l15) * 40 + quad * 8);
  }
  float4v s[4][4];
#pragma unroll
  for (int ni = 0; ni < 4; ++ni)
#pragma unroll
    for (int mi = 0; mi < 4; ++mi) {
      float4v z = {0.f, 0.f, 0.f, 0.f};
      s[ni][mi] = __builtin_amdgcn_mfma_f32_16x16x32_f16(aq[ni], bk[mi], z, 0, 0, 0);
    }
  const float* bh = btab + head * 4096;
#pragma unroll
  for (int ni = 0; ni < 4; ++ni)
#pragma unroll
    for (int i = 0; i < 4; ++i) {
      const int n = ni * 16 + quad * 4 + i;
#pragma unroll
      for (int mi = 0; mi < 4; ++mi) s[ni][mi][i] += bh[n * 64 + mi * 16 + l15];
    }
  float inv[4][4];
#pragma unroll
  for (int ni = 0; ni < 4; ++ni)
#pragma unroll
    for (int i = 0; i < 4; ++i) {
      float mx = fmaxf(fmaxf(s[ni][0][i], s[ni][1][i]), fmaxf(s[ni][2][i], s[ni][3][i]));
      for (int off = 1; off < 16; off <<= 1) mx = fmaxf(mx, __shfl_xor(mx, off));
      float sum = 0.f;
#pragma unroll
      for (int mi = 0; mi < 4; ++mi) {
        float e = __expf(s[ni][mi][i] - mx);
        s[ni][mi][i] = e;
        sum += e;
      }
      for (int off = 1; off < 16; off <<= 1) sum += __shfl_xor(sum, off);
      inv[ni][i] = 1.0f / sum;
    }
  // P -> scratch [n][72] (over q/k space; aq/bk already in registers)
#pragma unroll
  for (int ni = 0; ni < 4; ++ni)
#pragma unroll
    for (int i = 0; i < 4; ++i) {
      const int n = ni * 16 + quad * 4 + i;
#pragma unroll
      for (int mi = 0; mi < 4; ++mi)
        Psc[n * 72 + mi * 16 + l15] = (half_t)(s[ni][mi][i] * inv[ni][i]);
    }
  __builtin_amdgcn_s_waitcnt(0);  // P writes -> own reads

  // ---- PV: xa^T(c,n) = v(c,m) . P^T(m,n) ----
  half8 av[2][2];
#pragma unroll
  for (int ci = 0; ci < 2; ++ci)
#pragma unroll
    for (int k2 = 0; k2 < 2; ++k2)
      av[ci][k2] = *(const half8*)(vsc + (ci * 16 + l15) * 72 + k2 * 32 + quad * 8);
  float4v oa[2][4];
#pragma unroll
  for (int ci = 0; ci < 2; ++ci)
#pragma unroll
    for (int ni = 0; ni < 4; ++ni) {
      float4v z = {0.f, 0.f, 0.f, 0.f};
      oa[ci][ni] = z;
    }
#pragma unroll
  for (int ni = 0; ni < 4; ++ni)
#pragma unroll
    for (int k2 = 0; k2 < 2; ++k2) {
      half8 bp = *(const half8*)&Psc[(ni * 16 + l15) * 72 + k2 * 32 + quad * 8];
#pragma unroll
      for (int ci = 0; ci < 2; ++ci)
        oa[ci][ni] = __builtin_amdgcn_mfma_f32_16x16x32_f16(av[ci][k2], bp, oa[ci][ni], 0, 0, 0);
    }
  // store xa[px][c] fp16 (8B stores)
#pragma unroll
  for (int ci = 0; ci < 2; ++ci)
#pragma unroll
    for (int ni = 0; ni < 4; ++ni) {
      half4v h = {(half_t)oa[ci][ni].x, (half_t)oa[ci][ni].y,
                  (half_t)oa[ci][ni].z, (half_t)oa[ci][ni].w};
      *(half4v*)(xa + (size_t)(bd * 64 + ni * 16 + l15) * 256 + head * 32 + ci * 16 + quad * 4) = h;
    }
}

// ---------------- proj per-bd-slice ----------------
// grid 800, block 256. xa slice staged ONCE (full K=256, 1 barrier); W
// streamed from L2; fp32 transpose epilogue via LDS -> full 256B row stores.
__global__ __launch_bounds__(256) void proj_bd(
    const half_t* __restrict__ Wp, const half_t* __restrict__ xag,
    const float* __restrict__ projb, float* __restrict__ out32) {
  __shared__ __align__(16) char LSB[32768];
  half_t* xlp = (half_t*)LSB;
  float* T = (float*)LSB;                    // [64][68] overlay after K-loop
  const int bd = blockIdx.x;
  const int tid = threadIdx.x;
  const int wave = tid >> 6, lane = tid & 63;
  const int l15 = lane & 15, quad = lane >> 4;

  {
    const char* src = (const char*)(xag + (size_t)bd * 64 * 256);
#pragma unroll
    for (int i = 0; i < 8; ++i) {
      int row = i * 8 + wave * 2 + (lane >> 5);
      int sch = (lane & 31) ^ (row & 7);
      GLDS16(src + row * 512 + sch * 16, (char*)xlp + (i * 8 + wave * 2) * 512);
    }
  }
  __syncthreads();

  float4v acc[4][4];
#pragma unroll
  for (int mi = 0; mi < 4; ++mi)
#pragma unroll
    for (int ni = 0; ni < 4; ++ni) {
      float4v z = {0.f, 0.f, 0.f, 0.f};
      acc[mi][ni] = z;
    }
#pragma unroll
  for (int kh = 0; kh < 8; ++kh) {
    half8 af[4], bf[4];
#pragma unroll
    for (int mi = 0; mi < 4; ++mi)
      af[mi] = *(const half8*)(Wp + (wave * 64 + mi * 16 + l15) * 256 + kh * 32 + quad * 8);
#pragma unroll
    for (int ni = 0; ni < 4; ++ni) {
      int r = ni * 16 + l15;
      bf[ni] = *(const half8*)&xlp[r * 256 + (((kh * 4 + quad) ^ (r & 7)) * 8)];
    }
#pragma unroll
    for (int mi = 0; mi < 4; ++mi)
#pragma unroll
      for (int ni = 0; ni < 4; ++ni)
        acc[mi][ni] = __builtin_amdgcn_mfma_f32_16x16x32_f16(
            af[mi], bf[ni], acc[mi][ni], 0, 0, 0);
  }
  // + bias (into acc)
#pragma unroll
  for (int mi = 0; mi < 4; ++mi) {
    const float4v b4 = *(const float4v*)&projb[wave * 64 + mi * 16 + quad * 4];
#pragma unroll
    for (int ni = 0; ni < 4; ++ni) {
      acc[mi][ni].x += b4.x;
      acc[mi][ni].y += b4.y;
      acc[mi][ni].z += b4.z;
      acc[mi][ni].w += b4.w;
    }
  }

  const int b = bd / 100, d = bd % 100;
  const size_t bdbase = (size_t)b * 1638400 + (size_t)d * 64;
  const int tr = tid >> 2;                   // reader row 0..63
  const int col0 = (tid & 3) * 16;           // reader col base

  for (int r = 0; r < 4; ++r) {
    __syncthreads();                         // xlp dead (r=0) / prev round done
#pragma unroll
    for (int ni = 0; ni < 4; ++ni)
#pragma unroll
      for (int iv = 0; iv < 4; ++iv)
        T[(wave * 16 + quad * 4 + iv) * 68 + ni * 16 + l15] = acc[r][ni][iv];
    __syncthreads();
    const int o = (tr >> 4) * 64 + r * 16 + (tr & 15);
    float* dst = out32 + bdbase + (size_t)o * 6400 + col0;
    const float* srcT = &T[tr * 68 + col0];
#pragma unroll
    for (int j = 0; j < 4; ++j)
      *(float4v*)(dst + j * 4) = *(const float4v*)(srcT + j * 4);
  }
}

// ---------------- launch ----------------
extern "C" void kernel_launch(void* const* d_in, const int* in_sizes, int n_in,
                              void* d_out, int out_size, void* d_ws, size_t ws_size,
                              hipStream_t stream) {
  const float* x        = (const float*)d_in[0];
  const float* dwconv_w = (const float*)d_in[1];
  const float* dwconv_b = (const float*)d_in[2];
  const float* qkv_w    = (const float*)d_in[3];
  const float* qkv_b    = (const float*)d_in[4];
  const float* proj_w   = (const float*)d_in[5];
  const float* proj_b   = (const float*)d_in[6];
  const float* rpb      = (const float*)d_in[7];
  float* out = (float*)d_out;

  char* ws = (char*)d_ws;
  size_t off = 0;
  half_t* xpad = (half_t*)(ws + off); off += 40960000;   // 800*100*256 fp16
  half_t* xl   = (half_t*)(ws + off); off += 26214400;   // 51200*256 fp16
  half_t* xa   = (half_t*)(ws + off); off += 26214400;   // [p][c] fp16
  half_t* Wt   = (half_t*)(ws + off); off += 1179648;    // [9][256][256]
  half_t* qw16 = (half_t*)(ws + off); off += 393216;
  half_t* pw16 = (half_t*)(ws + off); off += 131072;
  float*  btab = (float*)(ws + off);  off += 131072;     // [8][64][64]

  prep_convw<<<2304, 256, 0, stream>>>(dwconv_w, Wt);
  prep_qkvw<<<768, 256, 0, stream>>>(qkv_w, qw16);
  prep_projw<<<256, 256, 0, stream>>>(proj_w, pw16);
  prep_bias<<<128, 256, 0, stream>>>(rpb, btab);
  prep_xpad<<<800, 256, 0, stream>>>(x, xpad);

  conv_kernel<<<800, 256, 0, stream>>>(Wt, xpad, dwconv_b, xl);
  fused_qkv_attn<<<800, 512, 0, stream>>>(xl, qw16, qkv_b, btab, xa);
  proj_bd<<<800, 256, 0, stream>>>(pw16, xa, proj_b, out);
}

// Round 5
// 302.690 us; speedup vs baseline: 1.0803x; 1.0803x over previous
//
#include <hip/hip_runtime.h>
#include <cstdint>
#include <cstddef>

// ---------------- problem constants ----------------
#define SCALEQ 0.17677669529663689f // 32^-0.5

typedef _Float16 half_t;
typedef _Float16 half8   __attribute__((ext_vector_type(8)));
typedef _Float16 half4v  __attribute__((ext_vector_type(4)));
typedef float    float4v __attribute__((ext_vector_type(4)));

#define GLDS16(gp, lp)                                                        \
  __builtin_amdgcn_global_load_lds(                                           \
      (const __attribute__((address_space(1))) void*)(gp),                    \
      (__attribute__((address_space(3))) void*)(lp), 16, 0, 0)

// ---------------- merged prep kernel ----------------
// blocks [0,800): xpad transpose; [800,944): convw; [944,1040): qkvw;
// [1040,1072): projw; [1072,1088): bias table. Branches are block-uniform.
__global__ __launch_bounds__(256) void prep_all(
    const float* __restrict__ x, const float* __restrict__ dwconv_w,
    const float* __restrict__ qkv_w, const float* __restrict__ proj_w,
    const float* __restrict__ rpb, half_t* __restrict__ xpad,
    half_t* __restrict__ Wt, half_t* __restrict__ qw16,
    half_t* __restrict__ pw16, float* __restrict__ btab) {
  __shared__ float tile[128 * 65];
  const int blk = blockIdx.x, t = threadIdx.x;
  if (blk < 800) {
    const int bd = blk, b = bd / 100, d = bd % 100;
    for (int hf = 0; hf < 2; ++hf) {
      for (int i = 0; i < 32; ++i) {
        int idx = i * 256 + t, c = idx >> 6, hw = idx & 63;
        tile[c * 65 + hw] = x[(size_t)((b * 256 + hf * 128 + c) * 100 + d) * 64 + hw];
      }
      __syncthreads();
      for (int i = 0; i < 50; ++i) {
        int idx = i * 256 + t, cell = idx >> 7, c = idx & 127;
        int hh = cell / 10, ww = cell % 10;
        float v = 0.f;
        if (hh >= 1 && hh <= 8 && ww >= 1 && ww <= 8)
          v = tile[c * 65 + (hh - 1) * 8 + (ww - 1)];
        xpad[(size_t)(bd * 100 + cell) * 256 + hf * 128 + c] = (half_t)v;
      }
      __syncthreads();
    }
  } else if (blk < 944) {        // convw: Wt[tap][o][c]
    const int base = (blk - 800) * 4096;
#pragma unroll
    for (int i = 0; i < 16; ++i) {
      int idx = base + i * 256 + t;
      int tap = idx >> 16, rem = idx & 65535;
      int o = rem >> 8, c = rem & 255;
      Wt[idx] = (half_t)dwconv_w[(o * 256 + c) * 9 + tap];
    }
  } else if (blk < 1040) {       // qkvw (q rows pre-scaled)
    const int base = (blk - 944) * 2048;
#pragma unroll
    for (int i = 0; i < 8; ++i) {
      int idx = base + i * 256 + t;
      float v = qkv_w[idx];
      if (idx < 65536) v *= SCALEQ;
      qw16[idx] = (half_t)v;
    }
  } else if (blk < 1072) {       // projw
    const int base = (blk - 1040) * 2048;
#pragma unroll
    for (int i = 0; i < 8; ++i) {
      int idx = base + i * 256 + t;
      pw16[idx] = (half_t)proj_w[idx];
    }
  } else {                       // bias table btab[head][n][m]
    const int base = (blk - 1072) * 2048;
#pragma unroll
    for (int i = 0; i < 8; ++i) {
      int idx = base + i * 256 + t;
      int hd = idx >> 12, n = (idx >> 6) & 63, m = idx & 63;
      int h1 = n >> 3, w1 = n & 7, h2 = m >> 3, w2 = m & 7;
      int ridx = (h1 - h2 + 7) * 15 + (w1 - w2 + 7);
      btab[idx] = rpb[ridx * 8 + hd];
    }
  }
}

// ---------------- conv implicit GEMM (unchanged, verified) ----------------
__global__ __launch_bounds__(256) void conv_kernel(
    const half_t* __restrict__ Wt, const half_t* __restrict__ xpad,
    const float* __restrict__ convb, half_t* __restrict__ xl) {
  __shared__ __align__(16) half_t Asm[128 * 64];
  __shared__ __align__(16) half_t Bsm[128 * 64];
  const int blk = blockIdx.x;
  const int o0 = (blk & 1) * 128;
  const int n0 = (blk >> 1) * 128;
  const int tid = threadIdx.x;
  const int wave = tid >> 6, lane = tid & 63;
  const int l15 = lane & 15, quad = lane >> 4;
  const int wm = wave >> 1, wn = wave & 1;
  const int srow = tid >> 3;
  const int cg = (tid & 7) ^ (srow & 7);

  int pixbase[4], arow[4];
#pragma unroll
  for (int i = 0; i < 4; ++i) {
    int P = n0 + srow + i * 32;
    int bd = P >> 6, hw = P & 63;
    pixbase[i] = (bd * 100 + (hw >> 3) * 10 + (hw & 7)) * 512 + cg * 16;
    arow[i] = (o0 + srow + i * 32) * 512 + cg * 16;
  }

  float4v acc[4][4];
#pragma unroll
  for (int mi = 0; mi < 4; ++mi)
#pragma unroll
    for (int ni = 0; ni < 4; ++ni) {
      float4v z = {0.f, 0.f, 0.f, 0.f};
      acc[mi][ni] = z;
    }

  const char* xpc = (const char*)xpad;
  for (int tap = 0; tap < 9; ++tap) {
    const char* wt = (const char*)Wt + tap * 131072;
    const int toff = ((tap / 3) * 10 + (tap % 3)) * 512;
    for (int c0 = 0; c0 < 512; c0 += 128) {
#pragma unroll
      for (int i = 0; i < 4; ++i) {
        GLDS16(wt + arow[i] + c0, (char*)Asm + i * 4096 + wave * 1024);
        GLDS16(xpc + pixbase[i] + toff + c0, (char*)Bsm + i * 4096 + wave * 1024);
      }
      __syncthreads();
#pragma unroll
      for (int kh = 0; kh < 2; ++kh) {
        half8 af[4], bf[4];
#pragma unroll
        for (int mi = 0; mi < 4; ++mi) {
          int r = wm * 64 + mi * 16 + l15;
          af[mi] = *(const half8*)&Asm[r * 64 + (((kh * 4 + quad) ^ (r & 7)) * 8)];
        }
#pragma unroll
        for (int ni = 0; ni < 4; ++ni) {
          int r = wn * 64 + ni * 16 + l15;
          bf[ni] = *(const half8*)&Bsm[r * 64 + (((kh * 4 + quad) ^ (r & 7)) * 8)];
        }
#pragma unroll
        for (int mi = 0; mi < 4; ++mi)
#pragma unroll
          for (int ni = 0; ni < 4; ++ni)
            acc[mi][ni] = __builtin_amdgcn_mfma_f32_16x16x32_f16(
                af[mi], bf[ni], acc[mi][ni], 0, 0, 0);
      }
      __syncthreads();
    }
  }
#pragma unroll
  for (int mi = 0; mi < 4; ++mi) {
    const int o4 = o0 + wm * 64 + mi * 16 + quad * 4;
    const float b0 = convb[o4], b1 = convb[o4 + 1], b2 = convb[o4 + 2], b3 = convb[o4 + 3];
#pragma unroll
    for (int ni = 0; ni < 4; ++ni) {
      const int P = n0 + wn * 64 + ni * 16 + l15;
      half4v h;
      h.x = (half_t)(acc[mi][ni].x + b0);
      h.y = (half_t)(acc[mi][ni].y + b1);
      h.z = (half_t)(acc[mi][ni].z + b2);
      h.w = (half_t)(acc[mi][ni].w + b3);
      *(half4v*)(xl + (size_t)P * 256 + o4) = h;
    }
  }
}

// ---------------- fused qkv + attention + proj ----------------
// grid 800 (one bd slice), block 512 (8 waves = 1 wave per head).
// LDS (halves): [0,16896) xlp [64px][256] swizzled, later xa [64px][264],
//               later T fp32 [64][68] (17408 B);
//               scratch at 16896 + wave*7680: q[64][40], k[64][40]@2560,
//               v[32][72]@5120, P[64][72]@0 (over q+k).
__global__ __launch_bounds__(512) void fused_tail2(
    const half_t* __restrict__ xlg, const half_t* __restrict__ qw,
    const float* __restrict__ qkvb, const float* __restrict__ btab,
    const half_t* __restrict__ pw, const float* __restrict__ projb,
    float* __restrict__ out32) {
  __shared__ __align__(16) half_t LS[78336];   // 156672 B
  const int bd = blockIdx.x;
  const int tid = threadIdx.x;
  const int wave = tid >> 6, lane = tid & 63;
  const int l15 = lane & 15, quad = lane >> 4;
  const int head = wave;

  half_t* xlp = LS;
  half_t* xa = LS;                      // [64][264] overlay after barrier
  float* T = (float*)LS;                // [64][68] fp32 overlay at the end
  half_t* scr = LS + 16896 + wave * 7680;
  half_t* qsc = scr;                    // [64][40]
  half_t* ksc = scr + 2560;             // [64][40]
  half_t* vsc = scr + 5120;             // [32][72]
  half_t* Psc = scr;                    // [64][72] (over q+k)

  // ---- stage xl[bd] (32 KB), XOR-swizzled 16B chunks ----
  {
    const char* src = (const char*)(xlg + (size_t)bd * 64 * 256);
#pragma unroll
    for (int i = 0; i < 4; ++i) {
      int row = i * 16 + wave * 2 + (lane >> 5);
      int sch = (lane & 31) ^ (row & 7);
      GLDS16(src + row * 512 + sch * 16, (char*)xlp + (i * 16 + wave * 2) * 512);
    }
  }
  __syncthreads();

  // ---- q and k GEMMs: M=32 (head rows), N=64 px, K=256 ----
  for (int p = 0; p < 2; ++p) {
    const half_t* Wp = qw + p * 65536 + head * 32 * 256;
    float4v acc[2][4];
#pragma unroll
    for (int mi = 0; mi < 2; ++mi)
#pragma unroll
      for (int ni = 0; ni < 4; ++ni) {
        float4v z = {0.f, 0.f, 0.f, 0.f};
        acc[mi][ni] = z;
      }
#pragma unroll
    for (int kh = 0; kh < 8; ++kh) {
      half8 af[2], bf[4];
#pragma unroll
      for (int mi = 0; mi < 2; ++mi)
        af[mi] = *(const half8*)(Wp + (mi * 16 + l15) * 256 + kh * 32 + quad * 8);
#pragma unroll
      for (int ni = 0; ni < 4; ++ni) {
        int r = ni * 16 + l15;
        bf[ni] = *(const half8*)&xlp[r * 256 + (((kh * 4 + quad) ^ (r & 7)) * 8)];
      }
#pragma unroll
      for (int mi = 0; mi < 2; ++mi)
#pragma unroll
        for (int ni = 0; ni < 4; ++ni)
          acc[mi][ni] = __builtin_amdgcn_mfma_f32_16x16x32_f16(
              af[mi], bf[ni], acc[mi][ni], 0, 0, 0);
    }
    half_t* dst = (p == 0) ? qsc : ksc;
    const float sc = (p == 0) ? SCALEQ : 1.0f;
#pragma unroll
    for (int mi = 0; mi < 2; ++mi) {
      const float4v b4 = *(const float4v*)&qkvb[p * 256 + head * 32 + mi * 16 + quad * 4];
#pragma unroll
      for (int ni = 0; ni < 4; ++ni) {
        half4v h;
        h.x = (half_t)(acc[mi][ni].x + b4.x * sc);
        h.y = (half_t)(acc[mi][ni].y + b4.y * sc);
        h.z = (half_t)(acc[mi][ni].z + b4.z * sc);
        h.w = (half_t)(acc[mi][ni].w + b4.w * sc);
        *(half4v*)(dst + (ni * 16 + l15) * 40 + mi * 16 + quad * 4) = h;
      }
    }
  }

  // ---- v GEMM: D[hd][px] -> vsc [32][72] ----
  {
    const half_t* Wp = qw + 2 * 65536 + head * 32 * 256;
    float4v acc[2][4];
#pragma unroll
    for (int mi = 0; mi < 2; ++mi)
#pragma unroll
      for (int ni = 0; ni < 4; ++ni) {
        float4v z = {0.f, 0.f, 0.f, 0.f};
        acc[mi][ni] = z;
      }
#pragma unroll
    for (int kh = 0; kh < 8; ++kh) {
      half8 af[2], bf[4];
#pragma unroll
      for (int mi = 0; mi < 2; ++mi)
        af[mi] = *(const half8*)(Wp + (mi * 16 + l15) * 256 + kh * 32 + quad * 8);
#pragma unroll
      for (int ni = 0; ni < 4; ++ni) {
        int r = ni * 16 + l15;
        bf[ni] = *(const half8*)&xlp[r * 256 + (((kh * 4 + quad) ^ (r & 7)) * 8)];
      }
#pragma unroll
      for (int mi = 0; mi < 2; ++mi)
#pragma unroll
        for (int ni = 0; ni < 4; ++ni)
          acc[mi][ni] = __builtin_amdgcn_mfma_f32_16x16x32_f16(
              af[mi], bf[ni], acc[mi][ni], 0, 0, 0);
    }
#pragma unroll
    for (int mi = 0; mi < 2; ++mi) {
      const float4v b4 = *(const float4v*)&qkvb[512 + head * 32 + mi * 16 + quad * 4];
#pragma unroll
      for (int ni = 0; ni < 4; ++ni) {
#pragma unroll
        for (int iv = 0; iv < 4; ++iv)
          vsc[(mi * 16 + quad * 4 + iv) * 72 + ni * 16 + l15] =
              (half_t)(acc[mi][ni][iv] + b4[iv]);
      }
    }
  }

  __builtin_amdgcn_s_waitcnt(0);  // q/k/v scratch writes -> own reads

  // ---- QK^T + bias + softmax ----
  half8 aq[4], bk[4];
#pragma unroll
  for (int i = 0; i < 4; ++i) {
    aq[i] = *(const half8*)(qsc + (i * 16 + l15) * 40 + quad * 8);
    bk[i] = *(const half8*)(ksc + (i * 16 + l15) * 40 + quad * 8);
  }
  float4v s[4][4];
#pragma unroll
  for (int ni = 0; ni < 4; ++ni)
#pragma unroll
    for (int mi = 0; mi < 4; ++mi) {
      float4v z = {0.f, 0.f, 0.f, 0.f};
      s[ni][mi] = __builtin_amdgcn_mfma_f32_16x16x32_f16(aq[ni], bk[mi], z, 0, 0, 0);
    }
  const float* bh = btab + head * 4096;
#pragma unroll
  for (int ni = 0; ni < 4; ++ni)
#pragma unroll
    for (int i = 0; i < 4; ++i) {
      const int n = ni * 16 + quad * 4 + i;
#pragma unroll
      for (int mi = 0; mi < 4; ++mi) s[ni][mi][i] += bh[n * 64 + mi * 16 + l15];
    }
  float inv[4][4];
#pragma unroll
  for (int ni = 0; ni < 4; ++ni)
#pragma unroll
    for (int i = 0; i < 4; ++i) {
      float mx = fmaxf(fmaxf(s[ni][0][i], s[ni][1][i]), fmaxf(s[ni][2][i], s[ni][3][i]));
      for (int off = 1; off < 16; off <<= 1) mx = fmaxf(mx, __shfl_xor(mx, off));
      float sum = 0.f;
#pragma unroll
      for (int mi = 0; mi < 4; ++mi) {
        float e = __expf(s[ni][mi][i] - mx);
        s[ni][mi][i] = e;
        sum += e;
      }
      for (int off = 1; off < 16; off <<= 1) sum += __shfl_xor(sum, off);
      inv[ni][i] = 1.0f / sum;
    }
#pragma unroll
  for (int ni = 0; ni < 4; ++ni)
#pragma unroll
    for (int i = 0; i < 4; ++i) {
      const int n = ni * 16 + quad * 4 + i;
#pragma unroll
      for (int mi = 0; mi < 4; ++mi)
        Psc[n * 72 + mi * 16 + l15] = (half_t)(s[ni][mi][i] * inv[ni][i]);
    }
  __builtin_amdgcn_s_waitcnt(0);  // P writes -> own reads

  // ---- PV ----
  half8 av[2][2];
#pragma unroll
  for (int ci = 0; ci < 2; ++ci)
#pragma unroll
    for (int k2 = 0; k2 < 2; ++k2)
      av[ci][k2] = *(const half8*)(vsc + (ci * 16 + l15) * 72 + k2 * 32 + quad * 8);
  float4v oa[2][4];
#pragma unroll
  for (int ci = 0; ci < 2; ++ci)
#pragma unroll
    for (int ni = 0; ni < 4; ++ni) {
      float4v z = {0.f, 0.f, 0.f, 0.f};
      oa[ci][ni] = z;
    }
#pragma unroll
  for (int ni = 0; ni < 4; ++ni)
#pragma unroll
    for (int k2 = 0; k2 < 2; ++k2) {
      half8 bp = *(const half8*)&Psc[(ni * 16 + l15) * 72 + k2 * 32 + quad * 8];
#pragma unroll
      for (int ci = 0; ci < 2; ++ci)
        oa[ci][ni] = __builtin_amdgcn_mfma_f32_16x16x32_f16(av[ci][k2], bp, oa[ci][ni], 0, 0, 0);
    }

  __syncthreads();  // all waves done reading xlp -> xa may overwrite it

  // ---- xa -> LDS [px][264] ----
#pragma unroll
  for (int ci = 0; ci < 2; ++ci)
#pragma unroll
    for (int ni = 0; ni < 4; ++ni) {
      half4v h = {(half_t)oa[ci][ni].x, (half_t)oa[ci][ni].y,
                  (half_t)oa[ci][ni].z, (half_t)oa[ci][ni].w};
      *(half4v*)(xa + (ni * 16 + l15) * 264 + head * 32 + ci * 16 + quad * 4) = h;
    }
  __syncthreads();

  // ---- proj: wave owns o-rows [32*wave, 32*wave+32) ----
  float4v pacc[2][4];
#pragma unroll
  for (int mi = 0; mi < 2; ++mi)
#pragma unroll
    for (int ni = 0; ni < 4; ++ni) {
      float4v z = {0.f, 0.f, 0.f, 0.f};
      pacc[mi][ni] = z;
    }
#pragma unroll
  for (int kh = 0; kh < 8; ++kh) {
    half8 af[2], bf[4];
#pragma unroll
    for (int mi = 0; mi < 2; ++mi)
      af[mi] = *(const half8*)(pw + (wave * 32 + mi * 16 + l15) * 256 + kh * 32 + quad * 8);
#pragma unroll
    for (int ni = 0; ni < 4; ++ni)
      bf[ni] = *(const half8*)&xa[(ni * 16 + l15) * 264 + kh * 32 + quad * 8];
#pragma unroll
    for (int mi = 0; mi < 2; ++mi)
#pragma unroll
      for (int ni = 0; ni < 4; ++ni)
        pacc[mi][ni] = __builtin_amdgcn_mfma_f32_16x16x32_f16(
            af[mi], bf[ni], pacc[mi][ni], 0, 0, 0);
  }
#pragma unroll
  for (int mi = 0; mi < 2; ++mi) {
    const float4v b4 = *(const float4v*)&projb[wave * 32 + mi * 16 + quad * 4];
#pragma unroll
    for (int ni = 0; ni < 4; ++ni) {
      pacc[mi][ni].x += b4.x;
      pacc[mi][ni].y += b4.y;
      pacc[mi][ni].z += b4.z;
      pacc[mi][ni].w += b4.w;
    }
  }

  // ---- transpose epilogue: 4 rounds of 64 o-rows via T[64][68] fp32 ----
  const int b = bd / 100, d = bd % 100;
  const size_t bdbase = (size_t)b * 1638400 + (size_t)d * 64;
  const int tr = tid >> 3;             // 0..63
  const int col0 = (tid & 7) * 8;
  for (int r = 0; r < 4; ++r) {
    __syncthreads();                   // r=0: also guards xa reads done
    if ((wave >> 1) == r) {
      const int rb = (wave & 1) * 32;
#pragma unroll
      for (int mi = 0; mi < 2; ++mi)
#pragma unroll
        for (int ni = 0; ni < 4; ++ni)
#pragma unroll
          for (int iv = 0; iv < 4; ++iv)
            T[(rb + mi * 16 + quad * 4 + iv) * 68 + ni * 16 + l15] = pacc[mi][ni][iv];
    }
    __syncthreads();
    const int o = r * 64 + tr;
    float* dst = out32 + bdbase + (size_t)o * 6400 + col0;
    const float* srcT = &T[tr * 68 + col0];
    *(float4v*)dst = *(const float4v*)srcT;
    *(float4v*)(dst + 4) = *(const float4v*)(srcT + 4);
  }
}

// ---------------- launch ----------------
extern "C" void kernel_launch(void* const* d_in, const int* in_sizes, int n_in,
                              void* d_out, int out_size, void* d_ws, size_t ws_size,
                              hipStream_t stream) {
  const float* x        = (const float*)d_in[0];
  const float* dwconv_w = (const float*)d_in[1];
  const float* dwconv_b = (const float*)d_in[2];
  const float* qkv_w    = (const float*)d_in[3];
  const float* qkv_b    = (const float*)d_in[4];
  const float* proj_w   = (const float*)d_in[5];
  const float* proj_b   = (const float*)d_in[6];
  const float* rpb      = (const float*)d_in[7];
  float* out = (float*)d_out;

  char* ws = (char*)d_ws;
  size_t off = 0;
  half_t* xpad = (half_t*)(ws + off); off += 40960000;   // 800*100*256 fp16
  half_t* xl   = (half_t*)(ws + off); off += 26214400;   // 51200*256 fp16
  half_t* Wt   = (half_t*)(ws + off); off += 1179648;    // [9][256][256]
  half_t* qw16 = (half_t*)(ws + off); off += 393216;
  half_t* pw16 = (half_t*)(ws + off); off += 131072;
  float*  btab = (float*)(ws + off);  off += 131072;     // [8][64][64]

  prep_all<<<1088, 256, 0, stream>>>(x, dwconv_w, qkv_w, proj_w, rpb,
                                     xpad, Wt, qw16, pw16, btab);
  conv_kernel<<<800, 256, 0, stream>>>(Wt, xpad, dwconv_b, xl);
  fused_tail2<<<800, 512, 0, stream>>>(xl, qw16, qkv_b, btab, pw16, proj_b, out);
}